// Round 1
// baseline (233.370 us; speedup 1.0000x reference)
//
#include <hip/hip_runtime.h>
#include <hip/hip_bf16.h>
#include <math.h>

// Causal scaled-dot-product attention, B=2 H=16 S=2048 D=64, fp32 in/out.
// Strategy: flash-attention with bf16 MFMA (16x16x32), 64-row q-blocks,
// 4 waves/block (16 q-rows per wave), KV tiles of 32 staged in LDS.

#define S_LEN 2048
#define D_DIM 64
#define QBLK  64
#define KVBLK 32
#define NTHREADS 256
#define SCALE 0.125f            // 1/sqrt(64)
#define L2E   1.4426950408889634f

// LDS row strides in bf16 elements; row byte stride must be a multiple of 16
// so ds_read_b128 fragments stay aligned.
#define KSTR 72   // K tile 32x64  -> 144 B/row
#define VSTR 40   // V^T tile 64x32 -> 80 B/row
#define PSTR 40   // P tile 16x32 per wave -> 80 B/row

typedef float f32x4 __attribute__((ext_vector_type(4)));
typedef __bf16 bf16x8 __attribute__((ext_vector_type(8)));
typedef unsigned short u16x8 __attribute__((ext_vector_type(8)));

static __device__ inline unsigned short f2bf(float f) {
  unsigned int u = __float_as_uint(f);
  u = u + 0x7FFFu + ((u >> 16) & 1u);   // round-to-nearest-even
  return (unsigned short)(u >> 16);
}

static __device__ inline bf16x8 pack8(const float* f) {
  u16x8 u;
#pragma unroll
  for (int i = 0; i < 8; ++i) u[i] = f2bf(f[i]);
  return __builtin_bit_cast(bf16x8, u);
}

__global__ __launch_bounds__(NTHREADS) void attn_fwd_kernel(
    const float* __restrict__ Qg, const float* __restrict__ Kg,
    const float* __restrict__ Vg, float* __restrict__ Og) {
  __shared__ unsigned short lds_k[KVBLK * KSTR];     // 32 x 64 bf16 (padded)
  __shared__ unsigned short lds_vt[D_DIM * VSTR];    // 64 x 32 bf16 (padded), V^T
  __shared__ unsigned short lds_p[4 * 16 * PSTR];    // per-wave 16 x 32 bf16 P

  const int tid  = threadIdx.x;
  const int lane = tid & 63;
  const int w    = tid >> 6;      // wave 0..3
  const int g    = lane >> 4;     // 4-lane-group index 0..3
  const int l15  = lane & 15;

  const int bh = blockIdx.y;
  const int q0 = blockIdx.x * QBLK;
  const size_t base = (size_t)bh * S_LEN * D_DIM;
  const float* Q = Qg + base;
  const float* K = Kg + base;
  const float* V = Vg + base;
  float*       O = Og + base;

  // ---- load this wave's Q fragments (16 rows x 64 cols, bf16) ----
  const int qrow_w = q0 + w * 16;
  bf16x8 qf[2];
  {
    const float* qp = Q + (size_t)(qrow_w + l15) * D_DIM + g * 8;
#pragma unroll
    for (int c = 0; c < 2; ++c) {
      float tmp[8];
      const float4 a = *reinterpret_cast<const float4*>(qp + c * 32);
      const float4 b = *reinterpret_cast<const float4*>(qp + c * 32 + 4);
      tmp[0] = a.x; tmp[1] = a.y; tmp[2] = a.z; tmp[3] = a.w;
      tmp[4] = b.x; tmp[5] = b.y; tmp[6] = b.z; tmp[7] = b.w;
      qf[c] = pack8(tmp);
    }
  }

  // ---- online-softmax state ----
  float m[4], l[4];
  f32x4 acc_o[4];
#pragma unroll
  for (int r = 0; r < 4; ++r) { m[r] = -INFINITY; l[r] = 0.0f; }
#pragma unroll
  for (int nt = 0; nt < 4; ++nt) acc_o[nt] = (f32x4)0.0f;

  const int ntiles = (q0 + QBLK) / KVBLK;   // causal: kv in [0, q0+64)

  for (int t = 0; t < ntiles; ++t) {
    const int kv0 = t * KVBLK;

    __syncthreads();   // previous iteration's LDS reads done
    // ---- stage K tile (row-major) and V tile (transposed) into LDS ----
    {
      const int r  = tid >> 3;          // 0..31 (kv row)
      const int c  = (tid & 7) * 8;     // 0..56 (d col)
      const float* kp = K + (size_t)(kv0 + r) * D_DIM + c;
      float tmp[8];
      {
        const float4 a = *reinterpret_cast<const float4*>(kp);
        const float4 b = *reinterpret_cast<const float4*>(kp + 4);
        tmp[0] = a.x; tmp[1] = a.y; tmp[2] = a.z; tmp[3] = a.w;
        tmp[4] = b.x; tmp[5] = b.y; tmp[6] = b.z; tmp[7] = b.w;
      }
      *reinterpret_cast<bf16x8*>(&lds_k[r * KSTR + c]) = pack8(tmp);

      const float* vp = V + (size_t)(kv0 + r) * D_DIM + c;
      const float4 a = *reinterpret_cast<const float4*>(vp);
      const float4 b = *reinterpret_cast<const float4*>(vp + 4);
      float vt[8] = {a.x, a.y, a.z, a.w, b.x, b.y, b.z, b.w};
#pragma unroll
      for (int i = 0; i < 8; ++i) lds_vt[(c + i) * VSTR + r] = f2bf(vt[i]);
    }
    __syncthreads();

    // ---- QK^T: S tile 16(q) x 32(kv), two 16-col MFMA n-tiles ----
    f32x4 sacc[2];
    sacc[0] = (f32x4)0.0f; sacc[1] = (f32x4)0.0f;
#pragma unroll
    for (int nt = 0; nt < 2; ++nt) {
#pragma unroll
      for (int c = 0; c < 2; ++c) {
        bf16x8 kf = *reinterpret_cast<const bf16x8*>(
            &lds_k[(nt * 16 + l15) * KSTR + c * 32 + g * 8]);
        sacc[nt] = __builtin_amdgcn_mfma_f32_16x16x32_bf16(qf[c], kf, sacc[nt], 0, 0, 0);
      }
    }

    // ---- mask + online softmax (wave-parallel, rows live in 16-lane groups) ----
    float p0[4], p1[4], fac[4];
#pragma unroll
    for (int r = 0; r < 4; ++r) {
      const int qg = qrow_w + g * 4 + r;
      float s0 = sacc[0][r] * SCALE;
      float s1 = sacc[1][r] * SCALE;
      if (kv0 + l15 > qg)      s0 = -INFINITY;
      if (kv0 + 16 + l15 > qg) s1 = -INFINITY;
      float tm = fmaxf(s0, s1);
      tm = fmaxf(tm, __shfl_xor(tm, 1));
      tm = fmaxf(tm, __shfl_xor(tm, 2));
      tm = fmaxf(tm, __shfl_xor(tm, 4));
      tm = fmaxf(tm, __shfl_xor(tm, 8));
      const float mn = fmaxf(m[r], tm);
      const float f  = exp2f((m[r] - mn) * L2E);
      p0[r] = exp2f((s0 - mn) * L2E);
      p1[r] = exp2f((s1 - mn) * L2E);
      float ps = p0[r] + p1[r];
      ps += __shfl_xor(ps, 1);
      ps += __shfl_xor(ps, 2);
      ps += __shfl_xor(ps, 4);
      ps += __shfl_xor(ps, 8);
      l[r] = l[r] * f + ps;
      m[r] = mn;
      fac[r] = f;
    }
#pragma unroll
    for (int nt = 0; nt < 4; ++nt) {
#pragma unroll
      for (int r = 0; r < 4; ++r) acc_o[nt][r] *= fac[r];
    }

    // ---- write P to wave-private LDS (C/D layout -> A-fragment layout) ----
    unsigned short* pw = &lds_p[w * 16 * PSTR];
#pragma unroll
    for (int r = 0; r < 4; ++r) {
      pw[(g * 4 + r) * PSTR + l15]      = f2bf(p0[r]);
      pw[(g * 4 + r) * PSTR + 16 + l15] = f2bf(p1[r]);
    }
    __syncthreads();   // P visible (also keeps lds_vt alive until all PV reads)

    // ---- PV: O += P(16x32) * V(32x64), 4 d-tiles of 16 ----
    bf16x8 pa = *reinterpret_cast<const bf16x8*>(&pw[l15 * PSTR + g * 8]);
#pragma unroll
    for (int nt = 0; nt < 4; ++nt) {
      bf16x8 vf = *reinterpret_cast<const bf16x8*>(
          &lds_vt[(nt * 16 + l15) * VSTR + g * 8]);
      acc_o[nt] = __builtin_amdgcn_mfma_f32_16x16x32_bf16(pa, vf, acc_o[nt], 0, 0, 0);
    }
  }

  // ---- epilogue: O = acc / l ----
#pragma unroll
  for (int nt = 0; nt < 4; ++nt) {
#pragma unroll
    for (int r = 0; r < 4; ++r) {
      const int qg = qrow_w + g * 4 + r;
      O[(size_t)qg * D_DIM + nt * 16 + l15] = acc_o[nt][r] / l[r];
    }
  }
}

extern "C" void kernel_launch(void* const* d_in, const int* in_sizes, int n_in,
                              void* d_out, int out_size, void* d_ws, size_t ws_size,
                              hipStream_t stream) {
  const float* q = (const float*)d_in[0];
  const float* k = (const float*)d_in[1];
  const float* v = (const float*)d_in[2];
  // d_in[3] is the causal mask; it is deterministic tril -> computed in-kernel.
  float* o = (float*)d_out;
  dim3 grid(S_LEN / QBLK, 2 * 16);   // 32 q-blocks x (B*H)=32
  attn_fwd_kernel<<<grid, NTHREADS, 0, stream>>>(q, k, v, o);
}

// Round 3
// 123.462 us; speedup vs baseline: 1.8902x; 1.8902x over previous
//
#include <hip/hip_runtime.h>
#include <hip/hip_bf16.h>
#include <math.h>

// Causal SDPA, B=2 H=16 S=2048 D=64, fp32 in/out.
// v2b: swapped QK^T (S^T in-register -> in-lane softmax), KVBLK=64,
// XOR-swizzled 128B-row LDS tiles, P via wave-private LDS, reversed q order.
// (v2 compile fix: pk2 via bit-level RNE, no __hip_bfloat162 bit_cast.)

#define S_LEN 2048
#define D_DIM 64
#define QBLK  64
#define KVBLK 64
#define NTH   256
#define L2E   1.4426950408889634f

typedef float f32x4 __attribute__((ext_vector_type(4)));
typedef __bf16 bf16x8 __attribute__((ext_vector_type(8)));

static __device__ inline unsigned int bfr(float f) {   // f32 -> bf16 bits (RNE)
  unsigned int u = __float_as_uint(f);
  return (u + 0x7FFFu + ((u >> 16) & 1u)) >> 16;
}
static __device__ inline unsigned int pk2(float a, float b) {
  return bfr(a) | (bfr(b) << 16);
}

// swizzled element offset in a [rows][64] bf16 LDS tile (128B rows):
// 16B granule index XORed with (row&7) -> bank-conflict floor for b128 ops.
static __device__ inline int swz(int row, int col) {
  return row * 64 + ((((col >> 3) ^ (row & 7)) << 3) | (col & 7));
}

__global__ __launch_bounds__(NTH, 4) void attn_fwd_kernel(
    const float* __restrict__ Qg, const float* __restrict__ Kg,
    const float* __restrict__ Vg, float* __restrict__ Og) {
  __shared__ unsigned short lds_k[KVBLK * 64];      // K[kv][d]   swizzled
  __shared__ unsigned short lds_v[D_DIM * KVBLK];   // V^T[d][kv] swizzled
  __shared__ unsigned short lds_p[4][16 * 64];      // per-wave P[q][kv] swizzled

  const int t = threadIdx.x;
  const int lane = t & 63, w = t >> 6, l15 = lane & 15, hi = lane >> 4;
  const int bh = blockIdx.y;
  const int q0 = ((int)gridDim.x - 1 - (int)blockIdx.x) * QBLK;  // big blocks first
  const size_t base = (size_t)bh * S_LEN * D_DIM;
  const float* Q = Qg + base;
  const float* K = Kg + base;
  const float* V = Vg + base;
  float*       O = Og + base;

  const int qrow_w = q0 + w * 16;

  // ---- Q fragments (16 rows this wave), pre-scaled by 1/sqrt(D)=0.125 ----
  bf16x8 qf[2];
  {
    const float* qp = Q + (size_t)(qrow_w + l15) * D_DIM + hi * 8;
#pragma unroll
    for (int kc = 0; kc < 2; ++kc) {
      float4 a = *(const float4*)(qp + kc * 32);
      float4 b = *(const float4*)(qp + kc * 32 + 4);
      unsigned int u0 = pk2(a.x * 0.125f, a.y * 0.125f);
      unsigned int u1 = pk2(a.z * 0.125f, a.w * 0.125f);
      unsigned int u2 = pk2(b.x * 0.125f, b.y * 0.125f);
      unsigned int u3 = pk2(b.z * 0.125f, b.w * 0.125f);
      uint4 u = { u0, u1, u2, u3 };
      qf[kc] = __builtin_bit_cast(bf16x8, u);
    }
  }

  float mL2 = -INFINITY, lsum = 0.0f;   // running max (in log2 units) and denom
  f32x4 acc[4];
#pragma unroll
  for (int nt = 0; nt < 4; ++nt) acc[nt] = (f32x4)0.0f;

  const int ntiles = q0 / KVBLK + 1;    // causal: kv in [0, q0+QBLK)
  for (int tt = 0; tt < ntiles; ++tt) {
    const int kv0 = tt * KVBLK;
    __syncthreads();                    // previous tile's LDS reads done

    // ---- stage K[kv][d] (64x64), 4 passes, fully coalesced float4 ----
#pragma unroll
    for (int pass = 0; pass < 4; ++pass) {
      int row = pass * 16 + (t >> 4);
      int c4  = (t & 15) * 4;
      float4 f = *(const float4*)(K + (size_t)(kv0 + row) * D_DIM + c4);
      uint2 u = { pk2(f.x, f.y), pk2(f.z, f.w) };
      *(uint2*)&lds_k[swz(row, c4)] = u;
    }
    // ---- stage V^T[d][kv] via coalesced float2 column loads ----
    {
      int d2 = (t & 31) * 2, kvq = t >> 5;
      float2 vv[8];
#pragma unroll
      for (int i = 0; i < 8; ++i)
        vv[i] = *(const float2*)(V + (size_t)(kv0 + kvq * 8 + i) * D_DIM + d2);
      uint4 ux = { pk2(vv[0].x, vv[1].x), pk2(vv[2].x, vv[3].x),
                   pk2(vv[4].x, vv[5].x), pk2(vv[6].x, vv[7].x) };
      uint4 uy = { pk2(vv[0].y, vv[1].y), pk2(vv[2].y, vv[3].y),
                   pk2(vv[4].y, vv[5].y), pk2(vv[6].y, vv[7].y) };
      *(uint4*)&lds_v[swz(d2, kvq * 8)]     = ux;
      *(uint4*)&lds_v[swz(d2 + 1, kvq * 8)] = uy;
    }
    __syncthreads();                    // tile staged

    if (kv0 <= qrow_w + 15) {           // skip fully-masked tiles (wave-uniform)
      // ---- S^T = K · Q^T : lane owns q = qrow_w + l15, kv = mt*16+hi*4+r ----
      f32x4 st[4];
#pragma unroll
      for (int mt = 0; mt < 4; ++mt) st[mt] = (f32x4)0.0f;
#pragma unroll
      for (int kc = 0; kc < 2; ++kc) {
#pragma unroll
        for (int mt = 0; mt < 4; ++mt) {
          bf16x8 kf = *(const bf16x8*)&lds_k[swz(mt * 16 + l15, kc * 32 + hi * 8)];
          st[mt] = __builtin_amdgcn_mfma_f32_16x16x32_bf16(kf, qf[kc], st[mt], 0, 0, 0);
        }
      }
      // ---- causal mask + online softmax, all in-register ----
      const int qg = qrow_w + l15;
      float s[16];
#pragma unroll
      for (int mt = 0; mt < 4; ++mt)
#pragma unroll
        for (int r = 0; r < 4; ++r) {
          int kv = kv0 + mt * 16 + hi * 4 + r;
          s[mt * 4 + r] = (kv <= qg) ? st[mt][r] : -INFINITY;
        }
      float tm = s[0];
#pragma unroll
      for (int i = 1; i < 16; ++i) tm = fmaxf(tm, s[i]);
      tm = fmaxf(tm, __shfl_xor(tm, 16));
      tm = fmaxf(tm, __shfl_xor(tm, 32));
      const float mn = fmaxf(mL2, tm * L2E);
      const float f  = exp2f(mL2 - mn);
      float p[16], ps = 0.0f;
#pragma unroll
      for (int i = 0; i < 16; ++i) { p[i] = exp2f(fmaf(s[i], L2E, -mn)); ps += p[i]; }
      ps += __shfl_xor(ps, 16);
      ps += __shfl_xor(ps, 32);
      lsum = lsum * f + ps;
      mL2 = mn;
      // ---- rescale O accumulator (acc rows are q = hi*4+r) ----
#pragma unroll
      for (int r = 0; r < 4; ++r) {
        float fr = __shfl(f, hi * 4 + r);
#pragma unroll
        for (int nt = 0; nt < 4; ++nt) acc[nt][r] *= fr;
      }
      // ---- P -> wave-private LDS (no barrier needed) ----
      unsigned short* pw = lds_p[w];
#pragma unroll
      for (int mt = 0; mt < 4; ++mt) {
        uint2 u = { pk2(p[mt * 4 + 0], p[mt * 4 + 1]),
                    pk2(p[mt * 4 + 2], p[mt * 4 + 3]) };
        *(uint2*)&pw[swz(l15, mt * 16 + hi * 4)] = u;
      }
      // ---- PV: O += P(16x64) · V(64x64) ----
#pragma unroll
      for (int kc = 0; kc < 2; ++kc) {
        bf16x8 pa = *(const bf16x8*)&pw[swz(l15, kc * 32 + hi * 8)];
#pragma unroll
        for (int nt = 0; nt < 4; ++nt) {
          bf16x8 vf = *(const bf16x8*)&lds_v[swz(nt * 16 + l15, kc * 32 + hi * 8)];
          acc[nt] = __builtin_amdgcn_mfma_f32_16x16x32_bf16(pa, vf, acc[nt], 0, 0, 0);
        }
      }
    }
  }

  // ---- epilogue: O = acc / l (l lives in lane l15 == q-local) ----
  float linv[4];
#pragma unroll
  for (int r = 0; r < 4; ++r) linv[r] = 1.0f / __shfl(lsum, hi * 4 + r);
#pragma unroll
  for (int nt = 0; nt < 4; ++nt)
#pragma unroll
    for (int r = 0; r < 4; ++r)
      O[(size_t)(qrow_w + hi * 4 + r) * D_DIM + nt * 16 + l15] = acc[nt][r] * linv[r];
}

extern "C" void kernel_launch(void* const* d_in, const int* in_sizes, int n_in,
                              void* d_out, int out_size, void* d_ws, size_t ws_size,
                              hipStream_t stream) {
  const float* q = (const float*)d_in[0];
  const float* k = (const float*)d_in[1];
  const float* v = (const float*)d_in[2];
  // d_in[3] (causal mask) is deterministic tril -> computed in-kernel.
  float* o = (float*)d_out;
  dim3 grid(S_LEN / QBLK, 2 * 16);
  attn_fwd_kernel<<<grid, NTH, 0, stream>>>(q, k, v, o);
}

// Round 4
// 96.495 us; speedup vs baseline: 2.4185x; 1.2795x over previous
//
#include <hip/hip_runtime.h>
#include <hip/hip_bf16.h>
#include <math.h>

// Causal SDPA, B=2 H=16 S=2048 D=64, fp32 in/out.
// v3: 32x32x16 MFMA, QBLK=128 (4 waves x 32 q-rows), swapped QK^T,
// in-register P via cvt_pk_bf16 + permlane32_swap (T12), deferred
// rescale (T13), XOR-swizzled K / V^T LDS tiles (16 KB), no P LDS.

#define S_LEN 2048
#define D_DIM 64
#define QBLK  128
#define KVBLK 64
#define NTH   256
#define L2E   1.4426950408889634f
#define THRL2 11.5f   // defer-rescale threshold (~= 8 nats) in log2 units

typedef float f32x16 __attribute__((ext_vector_type(16)));
typedef __bf16 bf16x8 __attribute__((ext_vector_type(8)));
typedef unsigned int uint2v __attribute__((ext_vector_type(2)));

static __device__ inline unsigned int bfr(float f) {   // f32 -> bf16 bits (RNE)
  unsigned int u = __float_as_uint(f);
  return (u + 0x7FFFu + ((u >> 16) & 1u)) >> 16;
}
static __device__ inline unsigned int pk2(float a, float b) {
  return bfr(a) | (bfr(b) << 16);
}
static __device__ inline unsigned int cvtpk(float lo, float hi) {
  unsigned int r;
  asm("v_cvt_pk_bf16_f32 %0, %1, %2" : "=v"(r) : "v"(lo), "v"(hi));
  return r;
}
// swizzled element offset in a [rows][64] bf16 LDS tile (128B rows)
static __device__ inline int swz(int row, int col) {
  return row * 64 + ((((col >> 3) ^ (row & 7)) << 3) | (col & 7));
}

__global__ __launch_bounds__(NTH, 2) void attn_fwd_kernel(
    const float* __restrict__ Qg, const float* __restrict__ Kg,
    const float* __restrict__ Vg, float* __restrict__ Og) {
  __shared__ unsigned short lds_k[KVBLK * 64];      // K[kv][d]   swizzled
  __shared__ unsigned short lds_v[D_DIM * KVBLK];   // V^T[d][kv] swizzled

  const int t = threadIdx.x;
  const int lane = t & 63, w = t >> 6, l31 = lane & 31, h = lane >> 5;
  const int bh = blockIdx.y;
  const int q0 = ((int)gridDim.x - 1 - (int)blockIdx.x) * QBLK;  // big first
  const size_t base = (size_t)bh * S_LEN * D_DIM;
  const float* Q = Qg + base;
  const float* K = Kg + base;
  const float* V = Vg + base;
  float*       O = Og + base;

  const int qrow_w = q0 + w * 32;
  const int qg = qrow_w + l31;          // this lane's q-row

  // ---- Q fragments (B operand: col q = lane&31, k = h*8+j), 4 k-chunks,
  //      pre-scaled by 1/sqrt(D)=0.125 ----
  bf16x8 qf[4];
  {
    const float* qp = Q + (size_t)qg * D_DIM + h * 8;
#pragma unroll
    for (int kc = 0; kc < 4; ++kc) {
      float4 a = *(const float4*)(qp + kc * 16);
      float4 b = *(const float4*)(qp + kc * 16 + 4);
      uint4 u = { pk2(a.x * 0.125f, a.y * 0.125f), pk2(a.z * 0.125f, a.w * 0.125f),
                  pk2(b.x * 0.125f, b.y * 0.125f), pk2(b.z * 0.125f, b.w * 0.125f) };
      qf[kc] = __builtin_bit_cast(bf16x8, u);
    }
  }

  float mL2 = -INFINITY, lsum = 0.0f;   // per-lane (q = l31) softmax state
  f32x16 acc[2];                        // O[32q][32d] halves, dh = 0,1
  acc[0] = (f32x16)0.0f; acc[1] = (f32x16)0.0f;

  const int ntiles = q0 / KVBLK + 2;    // kv in [0, q0+128)
  for (int tt = 0; tt < ntiles; ++tt) {
    const int kv0 = tt * KVBLK;
    __syncthreads();                    // previous tile's LDS reads done

    // ---- stage K[kv][d] (64x64 bf16), coalesced float4 ----
#pragma unroll
    for (int pass = 0; pass < 4; ++pass) {
      int row = pass * 16 + (t >> 4);
      int c4  = (t & 15) * 4;
      float4 f = *(const float4*)(K + (size_t)(kv0 + row) * D_DIM + c4);
      uint2 u = { pk2(f.x, f.y), pk2(f.z, f.w) };
      *(uint2*)&lds_k[swz(row, c4)] = u;
    }
    // ---- stage V^T[d][kv] via coalesced float2 column loads ----
    {
      int d2 = (t & 31) * 2, kvq = t >> 5;
      float2 vv[8];
#pragma unroll
      for (int i = 0; i < 8; ++i)
        vv[i] = *(const float2*)(V + (size_t)(kv0 + kvq * 8 + i) * D_DIM + d2);
      uint4 ux = { pk2(vv[0].x, vv[1].x), pk2(vv[2].x, vv[3].x),
                   pk2(vv[4].x, vv[5].x), pk2(vv[6].x, vv[7].x) };
      uint4 uy = { pk2(vv[0].y, vv[1].y), pk2(vv[2].y, vv[3].y),
                   pk2(vv[4].y, vv[5].y), pk2(vv[6].y, vv[7].y) };
      *(uint4*)&lds_v[swz(d2, kvq * 8)]     = ux;
      *(uint4*)&lds_v[swz(d2 + 1, kvq * 8)] = uy;
    }
    __syncthreads();                    // tile staged

    if (kv0 > qrow_w + 31) continue;    // fully masked for this wave

    // ---- S^T = K·Q^T : D[32kv][32q], lane owns col q = l31 ----
    f32x16 st[2];
    st[0] = (f32x16)0.0f; st[1] = (f32x16)0.0f;
#pragma unroll
    for (int kc = 0; kc < 4; ++kc) {
#pragma unroll
      for (int mt = 0; mt < 2; ++mt) {
        bf16x8 kf = *(const bf16x8*)&lds_k[swz(mt * 32 + l31, kc * 16 + h * 8)];
        st[mt] = __builtin_amdgcn_mfma_f32_32x32x16_bf16(kf, qf[kc], st[mt], 0, 0, 0);
      }
    }

    // ---- causal mask (in-place) + row max (lane holds 32 of 64 kv) ----
    float tm = -INFINITY;
#pragma unroll
    for (int mt = 0; mt < 2; ++mt)
#pragma unroll
      for (int r = 0; r < 16; ++r) {
        int kv = kv0 + mt * 32 + (r & 3) + 8 * (r >> 2) + 4 * h;
        float sv = (kv <= qg) ? st[mt][r] : -INFINITY;
        st[mt][r] = sv;
        tm = fmaxf(tm, sv);
      }
    tm = fmaxf(tm, __shfl_xor(tm, 32));   // other half of this q-row
    const float tmL2 = tm * L2E;

    // ---- deferred rescale (T13): only when max jumps by > THRL2 ----
    if (__any(tmL2 - mL2 > THRL2)) {
      const float mn = fmaxf(mL2, tmL2);
      const float f  = exp2f(mL2 - mn);   // 0 on first tile
      lsum *= f;
      mL2 = mn;
#pragma unroll
      for (int r = 0; r < 16; ++r) {
        const int mrow = (r & 3) + 8 * (r >> 2) + 4 * h;
        const float fr = __shfl(f, mrow);
        acc[0][r] *= fr;
        acc[1][r] *= fr;
      }
    }

    // ---- P = exp2(S*log2e - m), in place; row sum ----
    float ps = 0.0f;
#pragma unroll
    for (int mt = 0; mt < 2; ++mt)
#pragma unroll
      for (int r = 0; r < 16; ++r) {
        float p = exp2f(fmaf(st[mt][r], L2E, -mL2));
        st[mt][r] = p;
        ps += p;
      }
    ps += __shfl_xor(ps, 32);
    lsum += ps;

    // ---- PV: O[32q][64d] += P[32q][64kv]·V[64kv][64d], 4 k-chunks ----
    // A-frag built in-register: lane owns row q = l31; missing kv pairs
    // live on lane^32 -> cvt_pk + permlane32_swap (T12).
#pragma unroll
    for (int c = 0; c < 4; ++c) {
      const int p16 = c & 1;            // kv half within st[c>>1]
      const int rb = 8 * p16;
      unsigned int A0, A1, B0, B1;
      if (c < 2) {
        A0 = cvtpk(st[0][rb + 0], st[0][rb + 1]);
        A1 = cvtpk(st[0][rb + 2], st[0][rb + 3]);
        B0 = cvtpk(st[0][rb + 4], st[0][rb + 5]);
        B1 = cvtpk(st[0][rb + 6], st[0][rb + 7]);
      } else {
        A0 = cvtpk(st[1][rb + 0], st[1][rb + 1]);
        A1 = cvtpk(st[1][rb + 2], st[1][rb + 3]);
        B0 = cvtpk(st[1][rb + 4], st[1][rb + 5]);
        B1 = cvtpk(st[1][rb + 6], st[1][rb + 7]);
      }
      unsigned int W0, W1, W2, W3;
#if __has_builtin(__builtin_amdgcn_permlane32_swap)
      {
        uint2v r02 = __builtin_amdgcn_permlane32_swap(A0, B0, false, false);
        uint2v r13 = __builtin_amdgcn_permlane32_swap(A1, B1, false, false);
        W0 = r02[0]; W2 = r02[1];
        W1 = r13[0]; W3 = r13[1];
      }
#else
      {
        unsigned int sA0 = (unsigned int)__shfl_xor((int)A0, 32);
        unsigned int sB0 = (unsigned int)__shfl_xor((int)B0, 32);
        unsigned int sA1 = (unsigned int)__shfl_xor((int)A1, 32);
        unsigned int sB1 = (unsigned int)__shfl_xor((int)B1, 32);
        W0 = h ? sB0 : A0;  W2 = h ? B0 : sA0;
        W1 = h ? sB1 : A1;  W3 = h ? B1 : sA1;
      }
#endif
      uint4 uw = { W0, W1, W2, W3 };
      bf16x8 pa = __builtin_bit_cast(bf16x8, uw);
#pragma unroll
      for (int dh = 0; dh < 2; ++dh) {
        bf16x8 vf = *(const bf16x8*)&lds_v[swz(dh * 32 + l31, c * 16 + h * 8)];
        acc[dh] = __builtin_amdgcn_mfma_f32_32x32x16_bf16(pa, vf, acc[dh], 0, 0, 0);
      }
    }
  }

  // ---- epilogue: O = acc / lsum (lsum lives at lane q = l31) ----
  const float li = 1.0f / lsum;
#pragma unroll
  for (int r = 0; r < 16; ++r) {
    const int mrow = (r & 3) + 8 * (r >> 2) + 4 * h;
    const float lr = __shfl(li, mrow);
    float* op = O + (size_t)(qrow_w + mrow) * D_DIM + l31;
    op[0]  = acc[0][r] * lr;
    op[32] = acc[1][r] * lr;
  }
}

extern "C" void kernel_launch(void* const* d_in, const int* in_sizes, int n_in,
                              void* d_out, int out_size, void* d_ws, size_t ws_size,
                              hipStream_t stream) {
  const float* q = (const float*)d_in[0];
  const float* k = (const float*)d_in[1];
  const float* v = (const float*)d_in[2];
  // d_in[3] (causal mask) is deterministic tril -> computed in-kernel.
  float* o = (float*)d_out;
  dim3 grid(S_LEN / QBLK, 2 * 16);
  attn_fwd_kernel<<<grid, NTH, 0, stream>>>(q, k, v, o);
}

// Round 6
// 83.324 us; speedup vs baseline: 2.8007x; 1.1581x over previous
//
#include <hip/hip_runtime.h>
#include <hip/hip_bf16.h>
#include <math.h>

// Causal SDPA, B=2 H=16 S=2048 D=64, fp32 in/out.
// v5: v4 (split-KV, 8 waves = 4 q-strips x 2 interleaved KV halves) with the
// merge bug fixed: per-row shfl broadcast of the merge factors fA/fB
// (acc rows are mrow=(r&3)+8*(r>>2)+4h, not lane&31).

#define S_LEN 2048
#define D_DIM 64
#define QBLK  128
#define KVBLK 64
#define NTH   512
#define L2E   1.4426950408889634f
#define THRL2 11.5f

typedef float f32x16 __attribute__((ext_vector_type(16)));
typedef __bf16 bf16x8 __attribute__((ext_vector_type(8)));
typedef __bf16 bf16x4 __attribute__((ext_vector_type(4)));
typedef unsigned int uint2v __attribute__((ext_vector_type(2)));

static __device__ inline unsigned int cvtpk(float lo, float hi) {
  unsigned int r;
  asm("v_cvt_pk_bf16_f32 %0, %1, %2" : "=v"(r) : "v"(lo), "v"(hi));
  return r;
}
// swizzled element offset in a [rows][64] bf16 LDS tile (128B rows)
static __device__ inline int swz(int row, int col) {
  return row * 64 + ((((col >> 3) ^ (row & 7)) << 3) | (col & 7));
}

__global__ __launch_bounds__(NTH, 4) void attn_fwd_kernel(
    const float* __restrict__ Qg, const float* __restrict__ Kg,
    const float* __restrict__ Vg, float* __restrict__ Og) {
  __shared__ unsigned short lds_k[2][KVBLK * 64];    // per-half K[kv][d]
  __shared__ unsigned short lds_v[2][D_DIM * KVBLK]; // per-half V^T[d][kv]
  __shared__ float lds_ml[4][64][2];                 // merge: m, l of half=1

  const int t = threadIdx.x;
  const int lane = t & 63, w = t >> 6, l31 = lane & 31, h = lane >> 5;
  const int wq = w & 3, half = w >> 2;
  const int tl = t & 255;               // staging index within half-group
  const int bh = blockIdx.y;
  const int q0 = ((int)gridDim.x - 1 - (int)blockIdx.x) * QBLK;  // big first
  const size_t base = (size_t)bh * S_LEN * D_DIM;
  const float* Q = Qg + base;
  const float* K = Kg + base;
  const float* V = Vg + base;
  float*       O = Og + base;

  const int qrow_w = q0 + wq * 32;
  const int qg = qrow_w + l31;          // this lane's q-row

  // ---- Q fragments (B operand: col q = lane&31, k = h*8+j), x0.125 ----
  bf16x8 qf[4];
  {
    const float* qp = Q + (size_t)qg * D_DIM + h * 8;
#pragma unroll
    for (int kc = 0; kc < 4; ++kc) {
      float4 a = *(const float4*)(qp + kc * 16);
      float4 b = *(const float4*)(qp + kc * 16 + 4);
      bf16x8 q8;
      q8[0] = (__bf16)(a.x * 0.125f); q8[1] = (__bf16)(a.y * 0.125f);
      q8[2] = (__bf16)(a.z * 0.125f); q8[3] = (__bf16)(a.w * 0.125f);
      q8[4] = (__bf16)(b.x * 0.125f); q8[5] = (__bf16)(b.y * 0.125f);
      q8[6] = (__bf16)(b.z * 0.125f); q8[7] = (__bf16)(b.w * 0.125f);
      qf[kc] = q8;
    }
  }

  float mL2 = -INFINITY, lsum = 0.0f;   // per-lane (q = l31) softmax state
  f32x16 acc[2];                        // O[32q][32d] halves, dh = 0,1
  acc[0] = (f32x16)0.0f; acc[1] = (f32x16)0.0f;

  const int nit = q0 / 128 + 1;         // 128-wide kv super-tiles
  for (int it = 0; it < nit; ++it) {
    const int kv0 = it * 128 + half * 64;
    __syncthreads();                    // previous reads done (all waves)

    // ---- stage K[kv][d] (64x64 bf16) into this half's buffer ----
#pragma unroll
    for (int pass = 0; pass < 4; ++pass) {
      int row = pass * 16 + (tl >> 4);
      int c4  = (tl & 15) * 4;
      float4 f = *(const float4*)(K + (size_t)(kv0 + row) * D_DIM + c4);
      bf16x4 k4;
      k4[0] = (__bf16)f.x; k4[1] = (__bf16)f.y;
      k4[2] = (__bf16)f.z; k4[3] = (__bf16)f.w;
      *(bf16x4*)&lds_k[half][swz(row, c4)] = k4;
    }
    // ---- stage V^T[d][kv] via coalesced float2 column loads ----
    {
      int d2 = (tl & 31) * 2, kvq = tl >> 5;
      float2 vv[8];
#pragma unroll
      for (int i = 0; i < 8; ++i)
        vv[i] = *(const float2*)(V + (size_t)(kv0 + kvq * 8 + i) * D_DIM + d2);
      bf16x8 bx, by;
#pragma unroll
      for (int i = 0; i < 8; ++i) {
        bx[i] = (__bf16)vv[i].x;
        by[i] = (__bf16)vv[i].y;
      }
      *(bf16x8*)&lds_v[half][swz(d2, kvq * 8)]     = bx;
      *(bf16x8*)&lds_v[half][swz(d2 + 1, kvq * 8)] = by;
    }
    __syncthreads();                    // tile staged

    if (kv0 > qrow_w + 31) continue;    // fully masked for this wave

    // ---- S^T = K·Q^T : D[32kv][32q], lane owns col q = l31 ----
    f32x16 st[2];
    st[0] = (f32x16)0.0f; st[1] = (f32x16)0.0f;
#pragma unroll
    for (int kc = 0; kc < 4; ++kc) {
#pragma unroll
      for (int mt = 0; mt < 2; ++mt) {
        bf16x8 kf = *(const bf16x8*)&lds_k[half][swz(mt * 32 + l31, kc * 16 + h * 8)];
        st[mt] = __builtin_amdgcn_mfma_f32_32x32x16_bf16(kf, qf[kc], st[mt], 0, 0, 0);
      }
    }

    // ---- causal mask (diagonal tiles only) + row max ----
    float tm = -INFINITY;
    if (kv0 + KVBLK - 1 > qrow_w) {     // tile touches the diagonal
#pragma unroll
      for (int mt = 0; mt < 2; ++mt)
#pragma unroll
        for (int r = 0; r < 16; ++r) {
          int kv = kv0 + mt * 32 + (r & 3) + 8 * (r >> 2) + 4 * h;
          float sv = (kv <= qg) ? st[mt][r] : -INFINITY;
          st[mt][r] = sv;
          tm = fmaxf(tm, sv);
        }
    } else {
#pragma unroll
      for (int mt = 0; mt < 2; ++mt)
#pragma unroll
        for (int r = 0; r < 16; ++r) tm = fmaxf(tm, st[mt][r]);
    }
    tm = fmaxf(tm, __shfl_xor(tm, 32));
    const float tmL2 = tm * L2E;

    // ---- deferred rescale (T13) ----
    if (__any(tmL2 - mL2 > THRL2)) {
      const float mn = fmaxf(mL2, tmL2);
      const float f  = exp2f(mL2 - mn);
      lsum *= f;
      mL2 = mn;
#pragma unroll
      for (int r = 0; r < 16; ++r) {
        const int mrow = (r & 3) + 8 * (r >> 2) + 4 * h;
        const float fr = __shfl(f, mrow);
        acc[0][r] *= fr;
        acc[1][r] *= fr;
      }
    }

    // ---- P = exp2(S*L2E - m); row sum ----
    float ps = 0.0f;
#pragma unroll
    for (int mt = 0; mt < 2; ++mt)
#pragma unroll
      for (int r = 0; r < 16; ++r) {
        float p = exp2f(fmaf(st[mt][r], L2E, -mL2));
        st[mt][r] = p;
        ps += p;
      }
    ps += __shfl_xor(ps, 32);
    lsum += ps;

    // ---- PV: in-register A-frag via cvt_pk + permlane32_swap (T12) ----
#pragma unroll
    for (int c = 0; c < 4; ++c) {
      const int rb = 8 * (c & 1);
      const int m2 = c >> 1;
      unsigned int A0 = cvtpk(st[m2][rb + 0], st[m2][rb + 1]);
      unsigned int A1 = cvtpk(st[m2][rb + 2], st[m2][rb + 3]);
      unsigned int B0 = cvtpk(st[m2][rb + 4], st[m2][rb + 5]);
      unsigned int B1 = cvtpk(st[m2][rb + 6], st[m2][rb + 7]);
      unsigned int W0, W1, W2, W3;
#if __has_builtin(__builtin_amdgcn_permlane32_swap)
      {
        uint2v r02 = __builtin_amdgcn_permlane32_swap(A0, B0, false, false);
        uint2v r13 = __builtin_amdgcn_permlane32_swap(A1, B1, false, false);
        W0 = r02[0]; W2 = r02[1];
        W1 = r13[0]; W3 = r13[1];
      }
#else
      {
        unsigned int sA0 = (unsigned int)__shfl_xor((int)A0, 32);
        unsigned int sB0 = (unsigned int)__shfl_xor((int)B0, 32);
        unsigned int sA1 = (unsigned int)__shfl_xor((int)A1, 32);
        unsigned int sB1 = (unsigned int)__shfl_xor((int)B1, 32);
        W0 = h ? sB0 : A0;  W2 = h ? B0 : sA0;
        W1 = h ? sB1 : A1;  W3 = h ? B1 : sA1;
      }
#endif
      uint4 uw = { W0, W1, W2, W3 };
      bf16x8 pa = __builtin_bit_cast(bf16x8, uw);
#pragma unroll
      for (int dh = 0; dh < 2; ++dh) {
        bf16x8 vf = *(const bf16x8*)&lds_v[half][swz(dh * 32 + l31, c * 16 + h * 8)];
        acc[dh] = __builtin_amdgcn_mfma_f32_32x32x16_bf16(pa, vf, acc[dh], 0, 0, 0);
      }
    }
  }

  // ---- split-KV merge: half=1 state -> LDS (overlay staging bufs) ----
  float* accb0 = reinterpret_cast<float*>(lds_k);  // [4][64][16]
  float* accb1 = reinterpret_cast<float*>(lds_v);  // [4][64][16]
  __syncthreads();                                 // staging reads all done
  if (half == 1) {
    lds_ml[wq][lane][0] = mL2;
    lds_ml[wq][lane][1] = lsum;
    float* a0 = &accb0[(wq * 64 + lane) * 16];
    float* a1 = &accb1[(wq * 64 + lane) * 16];
#pragma unroll
    for (int r = 0; r < 16; ++r) { a0[r] = acc[0][r]; a1[r] = acc[1][r]; }
  }
  __syncthreads();
  if (half == 0) {
    const float mB = lds_ml[wq][lane][0];
    const float lB = lds_ml[wq][lane][1];
    const float mst = fmaxf(mL2, mB);
    const float fA = exp2f(mL2 - mst);
    const float fB = exp2f(mB - mst);
    const float lm = lsum * fA + lB * fB;
    const float li = 1.0f / lm;
    const float* a0 = &accb0[(wq * 64 + lane) * 16];
    const float* a1 = &accb1[(wq * 64 + lane) * 16];
#pragma unroll
    for (int r = 0; r < 16; ++r) {
      const int mrow = (r & 3) + 8 * (r >> 2) + 4 * h;
      const float fAr = __shfl(fA, mrow);   // FIX: factors are per-q-row,
      const float fBr = __shfl(fB, mrow);   // acc rows are mrow, not l31
      acc[0][r] = acc[0][r] * fAr + a0[r] * fBr;
      acc[1][r] = acc[1][r] * fAr + a1[r] * fBr;
      const float lr = __shfl(li, mrow);
      float* op = O + (size_t)(qrow_w + mrow) * D_DIM + l31;
      op[0]  = acc[0][r] * lr;
      op[32] = acc[1][r] * lr;
    }
  }
}

extern "C" void kernel_launch(void* const* d_in, const int* in_sizes, int n_in,
                              void* d_out, int out_size, void* d_ws, size_t ws_size,
                              hipStream_t stream) {
  const float* q = (const float*)d_in[0];
  const float* k = (const float*)d_in[1];
  const float* v = (const float*)d_in[2];
  // d_in[3] (causal mask) is deterministic tril -> computed in-kernel.
  float* o = (float*)d_out;
  dim3 grid(S_LEN / QBLK, 2 * 16);
  attn_fwd_kernel<<<grid, NTH, 0, stream>>>(q, k, v, o);
}